// Round 3
// baseline (332.589 us; speedup 1.0000x reference)
//
#include <hip/hip_runtime.h>
#include <math.h>

// S4D forward (conv mode) via chunked linear recurrence, t-tiled, n unrolled.
// y[b,l,d] = D[d]*x[b,l,d] + sum_n CB[d,n] * h_n[l],  h_n[l] = a_n h_n[l-1] + x[l]
// a = exp(dt*A), CB = C * expm1(dt*A)/A * B, A_n = -0.5*(n+1)
//
// P0 coef:  interleaved acb[n][d]={a,cb} + aT[n][d]=a^64 tables (d fastest).
// P1 state: per (b,c,d): u_n = zero-init end state of chunk. t tiled by 16,
//           h[64] loop-carried in regs, xv[16] pinned. ~90 VGPR.
// P2 scan:  s[c+1] = a^T s[c] + u[c] over 32 chunks (in-place; u -> s_start).
// P3 out:   h init = s_start, full recurrence + cb-dot + D-skip, y written
//           once. t tiled by 16: h[64]+xv[16]+acc[16] in regs. ~120 VGPR.

namespace {
constexpr int kBatch = 8;
constexpr int kLen   = 2048;
constexpr int kD     = 1024;
constexpr int kN     = 64;         // states
constexpr int kT     = 64;         // chunk length
constexpr int kTT    = 16;         // t-tile
constexpr int kC     = kLen / kT;  // 32 chunks

constexpr long kUElems  = (long)kBatch * kC * kN * kD;  // 16,777,216 floats
constexpr long kAcbOff  = kUElems;                      // acb[n][d][2]
constexpr long kAtOff   = kAcbOff + 2L * kN * kD;       // aT[n][d]
// total ws: (16777216 + 3*65536)*4 B = 67,895,296 B (~64.8 MiB)
}  // namespace

__global__ void s4d_coef_kernel(const float* __restrict__ log_dt,
                                const float* __restrict__ Bm,
                                const float* __restrict__ Cm,
                                float* __restrict__ ws) {
  int tid = blockIdx.x * blockDim.x + threadIdx.x;  // 65536 threads
  int d = tid & (kD - 1);
  int n = tid >> 10;
  float dt  = expf(log_dt[d]);
  float An  = -0.5f * (float)(n + 1);
  float dtA = dt * An;
  float a   = expf(dtA);
  float bbar = (expm1f(dtA) / An) * Bm[d * kN + n];
  float cb   = Cm[d * kN + n] * bbar;
  float aT   = expf(dtA * (float)kT);  // a^64
  ws[kAcbOff + 2L * ((long)n * kD + d)]     = a;
  ws[kAcbOff + 2L * ((long)n * kD + d) + 1] = cb;
  ws[kAtOff + (long)n * kD + d] = aT;
}

// Phase 1: chunk-local end states only (zero initial state).
__global__ __launch_bounds__(256) void s4d_state_kernel(
    const float* __restrict__ x, float* __restrict__ ws) {
  int tid = blockIdx.x * blockDim.x + threadIdx.x;  // 262144 threads
  int d  = tid & (kD - 1);   // consecutive lanes -> consecutive d: coalesced
  int bc = tid >> 10;
  int b  = bc >> 5;
  int c  = bc & (kC - 1);

  const float* xp = x + ((long)b * kLen + (long)c * kT) * kD + d;
  const float* ap = ws + kAcbOff + 2L * d;  // a at .x of interleaved table

  float h[kN];
#pragma unroll
  for (int n = 0; n < kN; ++n) h[n] = 0.f;

#pragma unroll 1
  for (int tt = 0; tt < kT / kTT; ++tt) {
    float xv[kTT];
#pragma unroll
    for (int t = 0; t < kTT; ++t) xv[t] = xp[(long)(tt * kTT + t) * kD];
#pragma unroll
    for (int t = 0; t < kTT; ++t) asm volatile("" : "+v"(xv[t]));  // pin
#pragma unroll
    for (int n = 0; n < kN; ++n) {
      float a = ap[2L * (long)n * kD];
      float hn = h[n];
#pragma unroll
      for (int t = 0; t < kTT; ++t) hn = fmaf(hn, a, xv[t]);
      h[n] = hn;
    }
  }
  float* up = ws + ((long)(b * kC + c) * kN) * kD + d;
#pragma unroll
  for (int n = 0; n < kN; ++n) up[(long)n * kD] = h[n];
}

// Phase 2: inter-chunk scan. After this, ws[u-region] holds s_start[c] =
// state at the END of chunk c-1 (i.e. initial state for chunk c).
__global__ void s4d_scan_kernel(float* __restrict__ ws) {
  int tid = blockIdx.x * blockDim.x + threadIdx.x;  // 524288 threads
  int d  = tid & (kD - 1);
  int bn = tid >> 10;
  int n  = bn & (kN - 1);
  int b  = bn >> 6;
  float aT = ws[kAtOff + (long)n * kD + d];
  float* up = ws + ((long)b * kC * kN + n) * kD + d;
  const long cstride = (long)kN * kD;
  float s = 0.f;
#pragma unroll 1
  for (int c = 0; c < kC; ++c) {
    float u = up[(long)c * cstride];
    up[(long)c * cstride] = s;  // in place: u[c] -> s_start[c]
    s = fmaf(aT, s, u);
  }
}

// Phase 3: full output. Recurrence with proper initial state, single y write.
__global__ __launch_bounds__(256) void s4d_out_kernel(
    const float* __restrict__ x, const float* __restrict__ Dv,
    float* __restrict__ y, const float* __restrict__ ws) {
  int tid = blockIdx.x * blockDim.x + threadIdx.x;  // 262144 threads
  int d  = tid & (kD - 1);
  int bc = tid >> 10;
  int b  = bc >> 5;
  int c  = bc & (kC - 1);

  const float2* acb = (const float2*)(ws + kAcbOff);
  const float*  sp  = ws + ((long)(b * kC + c) * kN) * kD + d;

  float h[kN];
#pragma unroll
  for (int n = 0; n < kN; ++n) h[n] = sp[(long)n * kD];  // initial state

  float Dd = Dv[d];
  const float* xp = x + ((long)b * kLen + (long)c * kT) * kD + d;
  float*       yp = y + ((long)b * kLen + (long)c * kT) * kD + d;

#pragma unroll 1
  for (int tt = 0; tt < kT / kTT; ++tt) {
    float xv[kTT];
#pragma unroll
    for (int t = 0; t < kTT; ++t) xv[t] = xp[(long)(tt * kTT + t) * kD];
#pragma unroll
    for (int t = 0; t < kTT; ++t) asm volatile("" : "+v"(xv[t]));  // pin
    float acc[kTT];
#pragma unroll
    for (int t = 0; t < kTT; ++t) acc[t] = Dd * xv[t];
#pragma unroll
    for (int n = 0; n < kN; ++n) {
      float2 ac = acb[(long)n * kD + d];  // {a, cb}
      float hn = h[n];
#pragma unroll
      for (int t = 0; t < kTT; ++t) {
        hn = fmaf(hn, ac.x, xv[t]);
        acc[t] = fmaf(ac.y, hn, acc[t]);
      }
      h[n] = hn;
    }
#pragma unroll
    for (int t = 0; t < kTT; ++t) yp[(long)(tt * kTT + t) * kD] = acc[t];
  }
}

extern "C" void kernel_launch(void* const* d_in, const int* in_sizes, int n_in,
                              void* d_out, int out_size, void* d_ws, size_t ws_size,
                              hipStream_t stream) {
  const float* x      = (const float*)d_in[0];
  const float* log_dt = (const float*)d_in[1];
  const float* Bm     = (const float*)d_in[2];
  const float* Cm     = (const float*)d_in[3];
  const float* Dv     = (const float*)d_in[4];
  float* y  = (float*)d_out;
  float* ws = (float*)d_ws;

  hipLaunchKernelGGL(s4d_coef_kernel, dim3((kN * kD) / 256), dim3(256), 0, stream,
                     log_dt, Bm, Cm, ws);
  hipLaunchKernelGGL(s4d_state_kernel, dim3((kBatch * kC * kD) / 256), dim3(256), 0, stream,
                     x, ws);
  hipLaunchKernelGGL(s4d_scan_kernel, dim3((kBatch * kN * kD) / 256), dim3(256), 0, stream,
                     ws);
  hipLaunchKernelGGL(s4d_out_kernel, dim3((kBatch * kC * kD) / 256), dim3(256), 0, stream,
                     x, Dv, y, ws);
}